// Round 2
// baseline (88.924 us; speedup 1.0000x reference)
//
#include <hip/hip_runtime.h>
#include <math.h>

// Problem constants (fixed by reference setup_inputs):
// support: (B, N, K, D) fp32, query: (B, Q, D) fp32
// out = concat(agg (B,N,D), qgw (B,N,K,1)) fp32
constexpr int B = 4;
constexpr int N = 10;
constexpr int K = 5;
constexpr int Q = 512;
constexpr int D = 1536;  // 2 * 768

constexpr int QCH = 8;           // query chunks (64 q each)
constexpr int DCH = 3;           // d chunks (512 floats = 128 float4 each)
// Workspace layout (floats), all slots WRITTEN by kernel 1 (no zero-init needed):
// [0, B*QCH*D)                 : qbar partials  (sum over 64 q's of query[b,q,d])
// [CS_OFF, CS_OFF + B*QCH*DCH) : csum partials  (sum of squares per block)
constexpr int CS_OFF = B * QCH * D;

// Kernel 1: partial query column sums + sum of squares. No atomics, no memset.
// grid = (QCH, DCH, B) = 96 blocks, block = 128. Thread handles one float4
// column across 64 queries.
__global__ __launch_bounds__(128) void qstats_kernel(
    const float* __restrict__ query, float* __restrict__ ws) {
    const int tid = threadIdx.x;
    const int qch = blockIdx.x;          // 0..7
    const int dch = blockIdx.y;          // 0..2
    const int b   = blockIdx.z;
    const int c   = dch * 128 + tid;     // float4 column, 0..383
    const int d   = c * 4;

    const float4* qp =
        (const float4*)(query + (size_t)b * Q * D + (size_t)qch * 64 * D + d);
    float4 acc = {0.f, 0.f, 0.f, 0.f};
    float ssq = 0.f;
#pragma unroll 4
    for (int q = 0; q < 64; ++q) {
        float4 v = qp[q * (D / 4)];
        acc.x += v.x; acc.y += v.y; acc.z += v.z; acc.w += v.w;
        ssq = fmaf(v.x, v.x, fmaf(v.y, v.y, fmaf(v.z, v.z, fmaf(v.w, v.w, ssq))));
    }
    float4* pp = (float4*)(ws + (size_t)(b * QCH + qch) * D + d);
    *pp = acc;

    // reduce ssq across the 2 waves of this block
    for (int off = 32; off > 0; off >>= 1) ssq += __shfl_down(ssq, off);
    __shared__ float red[2];
    const int wave = tid >> 6, lane = tid & 63;
    if (lane == 0) red[wave] = ssq;
    __syncthreads();
    if (tid == 0) ws[CS_OFF + (b * QCH + qch) * DCH + dch] = red[0] + red[1];
}

// Kernel 2: per (b,n) block — reduce partials into LDS qbar, dot products,
// tanh, softmax over K, write qgw, weighted shot-aggregation.
// grid = B*N = 40, block = 256.
__global__ __launch_bounds__(256) void agg_kernel(
    const float* __restrict__ support, const float* __restrict__ ws,
    float* __restrict__ out) {
    const int tid = threadIdx.x;
    const int bn  = blockIdx.x;          // 0..B*N-1
    const int b   = bn / N;

    const float* sup = support + (size_t)bn * K * D;

    __shared__ float s_qbar[D];
    __shared__ float s_red[2][K][4];
    __shared__ float s_w[K + 1];         // s_w[K] holds csum_b

    // qbar[d] = sum of QCH partials (L2-hot: 49 KB per block, shared across N)
    for (int d = tid; d < D; d += 256) {
        float s = 0.f;
#pragma unroll
        for (int j = 0; j < QCH; ++j) s += ws[(size_t)(b * QCH + j) * D + d];
        s_qbar[d] = s;
    }
    if (tid == 0) {
        float c = 0.f;
#pragma unroll
        for (int j = 0; j < QCH * DCH; ++j) c += ws[CS_OFF + b * QCH * DCH + j];
        s_w[K] = c;
    }
    __syncthreads();

    const int wave = tid >> 6, lane = tid & 63;
    for (int k = 0; k < K; ++k) {
        float a = 0.f, c = 0.f;
        for (int d = tid; d < D; d += 256) {
            float s = sup[k * D + d];
            a = fmaf(s, s, a);
            c = fmaf(s, s_qbar[d], c);
        }
        for (int off = 32; off > 0; off >>= 1) {
            a += __shfl_down(a, off);
            c += __shfl_down(c, off);
        }
        if (lane == 0) { s_red[0][k][wave] = a; s_red[1][k][wave] = c; }
    }
    __syncthreads();

    if (tid < K) {
        const int k = tid;
        float ssk = s_red[0][k][0] + s_red[0][k][1] + s_red[0][k][2] + s_red[0][k][3];
        float sqk = s_red[1][k][0] + s_red[1][k][1] + s_red[1][k][2] + s_red[1][k][3];
        float cb  = s_w[K] * (1.f / Q);
        // mean_q dist_sq = -||S||^2 + 2*S.qbar_mean - mean||q||^2
        float m = -ssk + 2.f * sqk * (1.f / Q) - cb;
        // note: write after all tid<K have read s_w[K]? tid k writes s_w[k],
        // k < K, so s_w[K] is never clobbered — no race.
        s_w[k] = tanhf(m);
    }
    __syncthreads();
    if (tid == 0) {
        float mx = s_w[0];
        for (int k = 1; k < K; ++k) mx = fmaxf(mx, s_w[k]);
        float e[K], sum = 0.f;
        for (int k = 0; k < K; ++k) { e[k] = expf(s_w[k] - mx); sum += e[k]; }
        float inv = 1.f / sum;
        for (int k = 0; k < K; ++k) s_w[k] = e[k] * inv;
    }
    __syncthreads();

    // qgw output (after agg block: B*N*D floats)
    if (tid < K) out[(size_t)B * N * D + bn * K + tid] = s_w[tid];

    float w[K];
#pragma unroll
    for (int k = 0; k < K; ++k) w[k] = s_w[k];

    for (int d = tid; d < D; d += 256) {
        float acc = 0.f;
#pragma unroll
        for (int k = 0; k < K; ++k) acc = fmaf(sup[k * D + d], w[k], acc);
        out[(size_t)bn * D + d] = acc;
    }
}

extern "C" void kernel_launch(void* const* d_in, const int* in_sizes, int n_in,
                              void* d_out, int out_size, void* d_ws, size_t ws_size,
                              hipStream_t stream) {
    const float* support = (const float*)d_in[0];
    const float* query   = (const float*)d_in[1];
    float* out = (float*)d_out;
    float* ws  = (float*)d_ws;

    dim3 g1(QCH, DCH, B);   // 96 blocks
    qstats_kernel<<<g1, 128, 0, stream>>>(query, ws);

    agg_kernel<<<B * N, 256, 0, stream>>>(support, ws, out);
}